// Round 14
// baseline (235.151 us; speedup 1.0000x reference)
//
#include <hip/hip_runtime.h>
#include <hip/hip_bf16.h>

#define BATCH 32
#define CIN   256
#define COUT  256
#define Hd    56
#define Wd    56
#define HW    (Hd*Wd)

typedef __attribute__((ext_vector_type(8))) short bf16x8;
typedef __attribute__((ext_vector_type(4))) float f32x4;

typedef const __attribute__((address_space(1))) void* gas1_t;
typedef __attribute__((address_space(3))) void* las3_t;

__device__ __forceinline__ unsigned short f2bf_rne(float f) {
    unsigned u = __builtin_bit_cast(unsigned, f);
    u += 0x7fffu + ((u >> 16) & 1u);
    return (unsigned short)(u >> 16);
}

// ---------------------------------------------------------------------------
// Fused prep (R12-proven): blocks [0,1856) xconv | [1856,1904) wprep |
// [1904,1936) bsum.
// ---------------------------------------------------------------------------
__global__ __launch_bounds__(512) void hetconv_prep_all(const float* __restrict__ x,
                                                        const float* __restrict__ W,
                                                        const float* __restrict__ bb_,
                                                        unsigned short* __restrict__ xb,
                                                        unsigned short* __restrict__ Wc3,
                                                        unsigned short* __restrict__ Wg3,
                                                        float* __restrict__ bsum) {
    const int bid = blockIdx.x;
    const int tid = threadIdx.x;
    const int lane = tid & 63;
    const int wid  = tid >> 6;

    if (bid < 1856) {                    // ---- xconv ----
        const int b  = bid / 58;
        const int pr = bid % 58;
        const int octG = tid >> 4;       // [0,32)
        const int q    = tid & 15;       // col quad; 14,15 write zeros
        const int pass = octG >> 4;
        const int g    = octG & 15;
        const int grow = pr - 1;
        const bool ok = (grow >= 0) && (grow < Hd) && (q < 14);
        const size_t base = ((size_t)(b * 2 + pass) * 58 + pr) * 8192;
        const float* xrow = x + (size_t)b * CIN * HW + (size_t)grow * Wd + q * 4;

        f32x4 v[8];
        #pragma unroll
        for (int e = 0; e < 8; ++e) {
            int kp = pass * 128 + g * 8 + e;
            int ic = ((kp & 63) << 2) | (kp >> 6);
            v[e] = ok ? *reinterpret_cast<const f32x4*>(xrow + (size_t)ic * HW)
                      : f32x4{0.f, 0.f, 0.f, 0.f};
        }
        #pragma unroll
        for (int i = 0; i < 4; ++i) {
            int col = q * 4 + i;
            bf16x8 pk;
            #pragma unroll
            for (int e = 0; e < 8; ++e) pk[e] = (short)f2bf_rne(v[e][i]);
            *reinterpret_cast<bf16x8*>(xb + base + col * 128 + ((g ^ (col & 7)) * 8)) = pk;
        }
    } else if (bid < 1904) {             // ---- wprep: 8 chunks per block ----
        const int u = (bid - 1856) * 8 + wid;    // [0,384)
        const int l15 = lane & 15;
        const int l4  = lane >> 4;
        if (u < 128) {                   // Wc3: chunk = ((r*2+p)*4+ks)*4+mf
            const int mf = u & 3;
            const int ks = (u >> 2) & 3;
            const int p  = (u >> 4) & 1;
            const int r  = u >> 5;
            const int np = r * 64 + mf * 16 + l15;
            const int n  = ((np & 63) << 2) | r;
            #pragma unroll
            for (int e = 0; e < 8; ++e) {
                int kp = p * 128 + ks * 32 + l4 * 8 + e;
                int ic = ((kp & 63) << 2) | (kp >> 6);
                Wc3[u * 512 + lane * 8 + e] = f2bf_rne(W[(n * CIN + ic) * 9 + 4]);
            }
        } else {                         // Wg3: chunk = ((r*8+t8)*2+ks2)*4+mf
            const int u2 = u - 128;
            const int mf  = u2 & 3;
            const int ks2 = (u2 >> 2) & 1;
            const int t8  = (u2 >> 3) & 7;
            const int r   = u2 >> 6;
            const int np = r * 64 + mf * 16 + l15;
            const int n  = ((np & 63) << 2) | r;
            const int tap = t8 + (t8 >= 4);
            #pragma unroll
            for (int e = 0; e < 8; ++e) {
                int j  = ks2 * 32 + l4 * 8 + e;
                int ic = (j << 2) | r;
                Wg3[u2 * 512 + lane * 8 + e] = f2bf_rne(W[(n * CIN + ic) * 9 + tap]);
            }
        }
    } else {                             // ---- bsum: 8 np per block ----
        const int np = (bid - 1904) * 8 + wid;   // [0,256)
        const int n = ((np & 63) << 2) | (np >> 6);
        float s = 0.f;
        for (int i = lane; i < CIN; i += 64) s += bb_[n * CIN + i];
        #pragma unroll
        for (int off = 32; off > 0; off >>= 1) s += __shfl_down(s, off, 64);
        if (lane == 0) bsum[np] = s;
    }
}

// ---------------------------------------------------------------------------
// Main: 256 persistent blocks (ONE round, no tail) = 32 b x 8 rowgroups of
// T = 4/3 two-row tiles.  1024 threads = 16 waves = (h, mh, r); per-wave
// tile 32 out-ch x 64 cols, acc[2][4] = 32 AGPR (R12-proven, no spill).
// Per tile: [stage both 64 KB slabs was issued earlier] vmcnt(0)+barrier ->
// unbroken dense+grouped MFMA stream -> syncthreads (slabs dead) ->
// issue NEXT tile's full 128 KB stage -> 4-round lf2 epilogue (stage lands
// under it) -> loop.  acc is consumed by the epilogue before the next
// compute, so no accumulator lives across the stage (R11's spill avoided).
// ---------------------------------------------------------------------------
__global__ __launch_bounds__(1024, 2) void hetconv_main(const unsigned short* __restrict__ xb,
                             const unsigned short* __restrict__ Wc3,
                             const unsigned short* __restrict__ Wg3,
                             const float* __restrict__ bsum,
                             float* __restrict__ y) {
    __shared__ unsigned short xs[2][32768];   // 2 x 64 KB pass slabs
    __shared__ float lf2[64 * 116];           // 29,696 B epilogue scratch

    const int bid = blockIdx.x;               // 256 blocks
    const int b   = bid >> 3;
    const int rg  = bid & 7;
    const int tr0 = (rg < 4) ? rg * 8 : 32 + (rg - 4) * 6;
    const int T   = (rg < 4) ? 4 : 3;

    const int tid  = threadIdx.x;
    const int lane = tid & 63;
    const int wid  = tid >> 6;        // [0,16)
    const int h  = wid & 1;
    const int mh = (wid >> 1) & 1;
    const int r  = wid >> 2;
    const int l15 = lane & 15;
    const int l4  = lane >> 4;

    auto STAGE2 = [&](int tr) {
        #pragma unroll
        for (int pass = 0; pass < 2; ++pass) {
            const unsigned short* slab = xb + ((size_t)(b * 2 + pass) * 58 + tr) * 8192;
            #pragma unroll
            for (int rd = 0; rd < 4; ++rd) {
                int vbase = rd * 1024 + wid * 64;     // 16B units, wave-uniform
                __builtin_amdgcn_global_load_lds(
                    (gas1_t)(slab + (size_t)(vbase + lane) * 8),
                    (las3_t)(xs[pass] + vbase * 8), 16, 0, 0);
            }
        }
    };

    STAGE2(tr0);
    asm volatile("s_waitcnt vmcnt(0)" ::: "memory");
    __builtin_amdgcn_s_barrier();

    for (int t = 0; t < T; ++t) {
        const int tr = tr0 + t * 2;

        f32x4 acc[2][4];
        #pragma unroll
        for (int i = 0; i < 2; ++i)
            #pragma unroll
            for (int j = 0; j < 4; ++j) acc[i][j] = f32x4{0.f, 0.f, 0.f, 0.f};

        // ---- both passes, one unbroken MFMA stream (R12-proven) ----
        #pragma unroll
        for (int pass = 0; pass < 2; ++pass) {
            const unsigned short* xsb = xs[pass];

            // dense center-tap GEMM: 4 K-steps of 32 channels
            {
                const int srow = (h + 1) * 64;
                #pragma unroll
                for (int ks = 0; ks < 4; ++ks) {
                    bf16x8 a[2];
                    #pragma unroll
                    for (int mf = 0; mf < 2; ++mf) {
                        int chunk = ((r * 2 + pass) * 4 + ks) * 4 + mh * 2 + mf;
                        a[mf] = *reinterpret_cast<const bf16x8*>(
                            Wc3 + ((size_t)chunk << 9) + lane * 8);
                    }
                    #pragma unroll
                    for (int nf = 0; nf < 4; ++nf) {
                        int s = srow + nf * 16 + l15;
                        int o = ks * 4 + l4;
                        int addr = s * 256 + ((o ^ (s & 7)) << 4);
                        bf16x8 bbv = *reinterpret_cast<const bf16x8*>(
                            reinterpret_cast<const char*>(xsb) + addr);
                        #pragma unroll
                        for (int mf = 0; mf < 2; ++mf)
                            acc[mf][nf] = __builtin_amdgcn_mfma_f32_16x16x32_bf16(
                                a[mf], bbv, acc[mf][nf], 0, 0, 0);
                    }
                }
            }

            // grouped off-center taps (waves whose residue is in this pass)
            if ((r >> 1) == pass) {
                const int cbase = (r & 1) * 64;
                #pragma unroll
                for (int t8 = 0; t8 < 8; ++t8) {
                    const int tap = t8 + (t8 >= 4);
                    const int dy = tap / 3 - 1;
                    const int dx = tap % 3 - 1;
                    const int srow = (h + 1 + dy) * 64;
                    #pragma unroll
                    for (int ks2 = 0; ks2 < 2; ++ks2) {
                        bf16x8 a[2];
                        #pragma unroll
                        for (int mf = 0; mf < 2; ++mf) {
                            int chunk = ((r * 8 + t8) * 2 + ks2) * 4 + mh * 2 + mf;
                            a[mf] = *reinterpret_cast<const bf16x8*>(
                                Wg3 + ((size_t)chunk << 9) + lane * 8);
                        }
                        #pragma unroll
                        for (int nf = 0; nf < 4; ++nf) {
                            int c2 = nf * 16 + l15 + dx;
                            c2 = ((unsigned)c2 < 64u) ? c2 : 56;   // col 56 is zero pad
                            int s = srow + c2;
                            int o = ((cbase + ks2 * 32) >> 3) + l4;
                            int addr = s * 256 + ((o ^ (s & 7)) << 4);
                            bf16x8 bbv = *reinterpret_cast<const bf16x8*>(
                                reinterpret_cast<const char*>(xsb) + addr);
                            #pragma unroll
                            for (int mf = 0; mf < 2; ++mf)
                                acc[mf][nf] = __builtin_amdgcn_mfma_f32_16x16x32_bf16(
                                    a[mf], bbv, acc[mf][nf], 0, 0, 0);
                        }
                    }
                }
            }
        }
        __syncthreads();                       // all slab reads complete

        // ---- issue next tile's full stage; it lands under the epilogue ----
        if (t + 1 < T) STAGE2(tr + 2);

        // ---- epilogue: 4 residue-rounds via lf2, coalesced f32x4 stores ----
        #pragma unroll
        for (int q = 0; q < 4; ++q) {
            if (r == q) {
                #pragma unroll
                for (int mf = 0; mf < 2; ++mf) {
                    #pragma unroll
                    for (int j = 0; j < 4; ++j) {
                        int npl = mh * 32 + mf * 16 + l4 * 4 + j;
                        float bias = bsum[q * 64 + npl];
                        #pragma unroll
                        for (int nf = 0; nf < 4; ++nf) {
                            int col = nf * 16 + l15;
                            if (col < Wd)
                                lf2[npl * 116 + h * 56 + col] = acc[mf][nf][j] + bias;
                        }
                    }
                }
            }
            __syncthreads();
            #pragma unroll
            for (int it = 0; it < 2; ++it) {
                int v = it * 1024 + tid;       // 64 npl x 28 float4
                if (v < 1792) {
                    int npl = v / 28;
                    int f   = v % 28;
                    int h2  = (f >= 14) ? 1 : 0;
                    int colS = (f - h2 * 14) * 4;
                    int n = (npl << 2) | q;
                    f32x4 val = *reinterpret_cast<const f32x4*>(lf2 + npl * 116 + f * 4);
                    *reinterpret_cast<f32x4*>(
                        y + (((size_t)b * COUT + n) * Hd + (tr + h2)) * Wd + colS) = val;
                }
            }
            __syncthreads();
        }

        if (t + 1 < T) {
            asm volatile("s_waitcnt vmcnt(0)" ::: "memory");
            __builtin_amdgcn_s_barrier();
        }
    }
}

extern "C" void kernel_launch(void* const* d_in, const int* in_sizes, int n_in,
                              void* d_out, int out_size, void* d_ws, size_t ws_size,
                              hipStream_t stream) {
    const float* x = (const float*)d_in[0];
    const float* W = (const float*)d_in[1];
    const float* b = (const float*)d_in[2];
    float* y = (float*)d_out;

    unsigned short* Wc3  = (unsigned short*)d_ws;                        // 131072 B
    unsigned short* Wg3  = (unsigned short*)((char*)d_ws + 131072);      // 262144 B
    float*          bsum = (float*)((char*)d_ws + 393216);               // 1024 B
    unsigned short* xb   = (unsigned short*)((char*)d_ws + 394240);      // 60,817,408 B

    hipLaunchKernelGGL(hetconv_prep_all, dim3(1936), dim3(512), 0, stream,
                       x, W, b, xb, Wc3, Wg3, bsum);
    hipLaunchKernelGGL(hetconv_main, dim3(256), dim3(1024), 0, stream,
                       xb, Wc3, Wg3, bsum, y);
}

// Round 15
// 234.694 us; speedup vs baseline: 1.0019x; 1.0019x over previous
//
#include <hip/hip_runtime.h>
#include <hip/hip_bf16.h>

#define BATCH 32
#define CIN   256
#define COUT  256
#define Hd    56
#define Wd    56
#define HW    (Hd*Wd)

typedef __attribute__((ext_vector_type(8))) short bf16x8;
typedef __attribute__((ext_vector_type(4))) float f32x4;

typedef const __attribute__((address_space(1))) void* gas1_t;
typedef __attribute__((address_space(3))) void* las3_t;

__device__ __forceinline__ unsigned short f2bf_rne(float f) {
    unsigned u = __builtin_bit_cast(unsigned, f);
    u += 0x7fffu + ((u >> 16) & 1u);
    return (unsigned short)(u >> 16);
}

// ---------------------------------------------------------------------------
// Fused prep (R12-proven): blocks [0,1856) xconv | [1856,1904) wprep |
// [1904,1936) bsum.
// ---------------------------------------------------------------------------
__global__ __launch_bounds__(512) void hetconv_prep_all(const float* __restrict__ x,
                                                        const float* __restrict__ W,
                                                        const float* __restrict__ bb_,
                                                        unsigned short* __restrict__ xb,
                                                        unsigned short* __restrict__ Wc3,
                                                        unsigned short* __restrict__ Wg3,
                                                        float* __restrict__ bsum) {
    const int bid = blockIdx.x;
    const int tid = threadIdx.x;
    const int lane = tid & 63;
    const int wid  = tid >> 6;

    if (bid < 1856) {                    // ---- xconv ----
        const int b  = bid / 58;
        const int pr = bid % 58;
        const int octG = tid >> 4;       // [0,32)
        const int q    = tid & 15;       // col quad; 14,15 write zeros
        const int pass = octG >> 4;
        const int g    = octG & 15;
        const int grow = pr - 1;
        const bool ok = (grow >= 0) && (grow < Hd) && (q < 14);
        const size_t base = ((size_t)(b * 2 + pass) * 58 + pr) * 8192;
        const float* xrow = x + (size_t)b * CIN * HW + (size_t)grow * Wd + q * 4;

        f32x4 v[8];
        #pragma unroll
        for (int e = 0; e < 8; ++e) {
            int kp = pass * 128 + g * 8 + e;
            int ic = ((kp & 63) << 2) | (kp >> 6);
            v[e] = ok ? *reinterpret_cast<const f32x4*>(xrow + (size_t)ic * HW)
                      : f32x4{0.f, 0.f, 0.f, 0.f};
        }
        #pragma unroll
        for (int i = 0; i < 4; ++i) {
            int col = q * 4 + i;
            bf16x8 pk;
            #pragma unroll
            for (int e = 0; e < 8; ++e) pk[e] = (short)f2bf_rne(v[e][i]);
            *reinterpret_cast<bf16x8*>(xb + base + col * 128 + ((g ^ (col & 7)) * 8)) = pk;
        }
    } else if (bid < 1904) {             // ---- wprep: 8 chunks per block ----
        const int u = (bid - 1856) * 8 + wid;    // [0,384)
        const int l15 = lane & 15;
        const int l4  = lane >> 4;
        if (u < 128) {                   // Wc3: chunk = ((r*2+p)*4+ks)*4+mf
            const int mf = u & 3;
            const int ks = (u >> 2) & 3;
            const int p  = (u >> 4) & 1;
            const int r  = u >> 5;
            const int np = r * 64 + mf * 16 + l15;
            const int n  = ((np & 63) << 2) | r;
            #pragma unroll
            for (int e = 0; e < 8; ++e) {
                int kp = p * 128 + ks * 32 + l4 * 8 + e;
                int ic = ((kp & 63) << 2) | (kp >> 6);
                Wc3[u * 512 + lane * 8 + e] = f2bf_rne(W[(n * CIN + ic) * 9 + 4]);
            }
        } else {                         // Wg3: chunk = ((r*8+t8)*2+ks2)*4+mf
            const int u2 = u - 128;
            const int mf  = u2 & 3;
            const int ks2 = (u2 >> 2) & 1;
            const int t8  = (u2 >> 3) & 7;
            const int r   = u2 >> 6;
            const int np = r * 64 + mf * 16 + l15;
            const int n  = ((np & 63) << 2) | r;
            const int tap = t8 + (t8 >= 4);
            #pragma unroll
            for (int e = 0; e < 8; ++e) {
                int j  = ks2 * 32 + l4 * 8 + e;
                int ic = (j << 2) | r;
                Wg3[u2 * 512 + lane * 8 + e] = f2bf_rne(W[(n * CIN + ic) * 9 + tap]);
            }
        }
    } else {                             // ---- bsum: 8 np per block ----
        const int np = (bid - 1904) * 8 + wid;   // [0,256)
        const int n = ((np & 63) << 2) | (np >> 6);
        float s = 0.f;
        for (int i = lane; i < CIN; i += 64) s += bb_[n * CIN + i];
        #pragma unroll
        for (int off = 32; off > 0; off >>= 1) s += __shfl_down(s, off, 64);
        if (lane == 0) bsum[np] = s;
    }
}

// ---------------------------------------------------------------------------
// Main: 256 persistent blocks (ONE round, no tail) = 32 b x 8 rowgroups of
// T = 4/3 two-row tiles.  1024 threads = 16 waves = (h, mh, r); per-wave
// tile 32 out-ch x 64 cols, acc[2][4] = 32 AGPR.
// __launch_bounds__(1024, 1): empirically cap = 128 regs (the (1024,2)
// 64-reg cap is what made R14 spill; R4/R6/R7/R12 calibrate the table).
// Per tile: vmcnt(0)+barrier -> unbroken dense+grouped MFMA stream ->
// syncthreads (slabs dead) -> issue NEXT tile's full 128 KB stage ->
// 4-round lf2 epilogue (stage lands under it) -> loop.
// ---------------------------------------------------------------------------
__global__ __launch_bounds__(1024, 1) void hetconv_main(const unsigned short* __restrict__ xb,
                             const unsigned short* __restrict__ Wc3,
                             const unsigned short* __restrict__ Wg3,
                             const float* __restrict__ bsum,
                             float* __restrict__ y) {
    __shared__ unsigned short xs[2][32768];   // 2 x 64 KB pass slabs
    __shared__ float lf2[64 * 116];           // 29,696 B epilogue scratch

    const int bid = blockIdx.x;               // 256 blocks
    const int b   = bid >> 3;
    const int rg  = bid & 7;
    const int tr0 = (rg < 4) ? rg * 8 : 32 + (rg - 4) * 6;
    const int T   = (rg < 4) ? 4 : 3;

    const int tid  = threadIdx.x;
    const int lane = tid & 63;
    const int wid  = tid >> 6;        // [0,16)
    const int h  = wid & 1;
    const int mh = (wid >> 1) & 1;
    const int r  = wid >> 2;
    const int l15 = lane & 15;
    const int l4  = lane >> 4;

    auto STAGE2 = [&](int tr) {
        #pragma unroll
        for (int pass = 0; pass < 2; ++pass) {
            const unsigned short* slab = xb + ((size_t)(b * 2 + pass) * 58 + tr) * 8192;
            #pragma unroll
            for (int rd = 0; rd < 4; ++rd) {
                int vbase = rd * 1024 + wid * 64;     // 16B units, wave-uniform
                __builtin_amdgcn_global_load_lds(
                    (gas1_t)(slab + (size_t)(vbase + lane) * 8),
                    (las3_t)(xs[pass] + vbase * 8), 16, 0, 0);
            }
        }
    };

    STAGE2(tr0);
    asm volatile("s_waitcnt vmcnt(0)" ::: "memory");
    __builtin_amdgcn_s_barrier();

    for (int t = 0; t < T; ++t) {
        const int tr = tr0 + t * 2;

        f32x4 acc[2][4];
        #pragma unroll
        for (int i = 0; i < 2; ++i)
            #pragma unroll
            for (int j = 0; j < 4; ++j) acc[i][j] = f32x4{0.f, 0.f, 0.f, 0.f};

        // ---- both passes, one unbroken MFMA stream (R12-proven) ----
        #pragma unroll
        for (int pass = 0; pass < 2; ++pass) {
            const unsigned short* xsb = xs[pass];

            // dense center-tap GEMM: 4 K-steps of 32 channels
            {
                const int srow = (h + 1) * 64;
                #pragma unroll
                for (int ks = 0; ks < 4; ++ks) {
                    bf16x8 a[2];
                    #pragma unroll
                    for (int mf = 0; mf < 2; ++mf) {
                        int chunk = ((r * 2 + pass) * 4 + ks) * 4 + mh * 2 + mf;
                        a[mf] = *reinterpret_cast<const bf16x8*>(
                            Wc3 + ((size_t)chunk << 9) + lane * 8);
                    }
                    #pragma unroll
                    for (int nf = 0; nf < 4; ++nf) {
                        int s = srow + nf * 16 + l15;
                        int o = ks * 4 + l4;
                        int addr = s * 256 + ((o ^ (s & 7)) << 4);
                        bf16x8 bbv = *reinterpret_cast<const bf16x8*>(
                            reinterpret_cast<const char*>(xsb) + addr);
                        #pragma unroll
                        for (int mf = 0; mf < 2; ++mf)
                            acc[mf][nf] = __builtin_amdgcn_mfma_f32_16x16x32_bf16(
                                a[mf], bbv, acc[mf][nf], 0, 0, 0);
                    }
                }
            }

            // grouped off-center taps (waves whose residue is in this pass)
            if ((r >> 1) == pass) {
                const int cbase = (r & 1) * 64;
                #pragma unroll
                for (int t8 = 0; t8 < 8; ++t8) {
                    const int tap = t8 + (t8 >= 4);
                    const int dy = tap / 3 - 1;
                    const int dx = tap % 3 - 1;
                    const int srow = (h + 1 + dy) * 64;
                    #pragma unroll
                    for (int ks2 = 0; ks2 < 2; ++ks2) {
                        bf16x8 a[2];
                        #pragma unroll
                        for (int mf = 0; mf < 2; ++mf) {
                            int chunk = ((r * 8 + t8) * 2 + ks2) * 4 + mh * 2 + mf;
                            a[mf] = *reinterpret_cast<const bf16x8*>(
                                Wg3 + ((size_t)chunk << 9) + lane * 8);
                        }
                        #pragma unroll
                        for (int nf = 0; nf < 4; ++nf) {
                            int c2 = nf * 16 + l15 + dx;
                            c2 = ((unsigned)c2 < 64u) ? c2 : 56;   // col 56 is zero pad
                            int s = srow + c2;
                            int o = ((cbase + ks2 * 32) >> 3) + l4;
                            int addr = s * 256 + ((o ^ (s & 7)) << 4);
                            bf16x8 bbv = *reinterpret_cast<const bf16x8*>(
                                reinterpret_cast<const char*>(xsb) + addr);
                            #pragma unroll
                            for (int mf = 0; mf < 2; ++mf)
                                acc[mf][nf] = __builtin_amdgcn_mfma_f32_16x16x32_bf16(
                                    a[mf], bbv, acc[mf][nf], 0, 0, 0);
                        }
                    }
                }
            }
        }
        __syncthreads();                       // all slab reads complete

        // ---- issue next tile's full stage; it lands under the epilogue ----
        if (t + 1 < T) STAGE2(tr + 2);

        // ---- epilogue: 4 residue-rounds via lf2, coalesced f32x4 stores ----
        #pragma unroll
        for (int q = 0; q < 4; ++q) {
            if (r == q) {
                #pragma unroll
                for (int mf = 0; mf < 2; ++mf) {
                    #pragma unroll
                    for (int j = 0; j < 4; ++j) {
                        int npl = mh * 32 + mf * 16 + l4 * 4 + j;
                        float bias = bsum[q * 64 + npl];
                        #pragma unroll
                        for (int nf = 0; nf < 4; ++nf) {
                            int col = nf * 16 + l15;
                            if (col < Wd)
                                lf2[npl * 116 + h * 56 + col] = acc[mf][nf][j] + bias;
                        }
                    }
                }
            }
            __syncthreads();
            #pragma unroll
            for (int it = 0; it < 2; ++it) {
                int v = it * 1024 + tid;       // 64 npl x 28 float4
                if (v < 1792) {
                    int npl = v / 28;
                    int f   = v % 28;
                    int h2  = (f >= 14) ? 1 : 0;
                    int colS = (f - h2 * 14) * 4;
                    int n = (npl << 2) | q;
                    f32x4 val = *reinterpret_cast<const f32x4*>(lf2 + npl * 116 + f * 4);
                    *reinterpret_cast<f32x4*>(
                        y + (((size_t)b * COUT + n) * Hd + (tr + h2)) * Wd + colS) = val;
                }
            }
            __syncthreads();
        }

        if (t + 1 < T) {
            asm volatile("s_waitcnt vmcnt(0)" ::: "memory");
            __builtin_amdgcn_s_barrier();
        }
    }
}

extern "C" void kernel_launch(void* const* d_in, const int* in_sizes, int n_in,
                              void* d_out, int out_size, void* d_ws, size_t ws_size,
                              hipStream_t stream) {
    const float* x = (const float*)d_in[0];
    const float* W = (const float*)d_in[1];
    const float* b = (const float*)d_in[2];
    float* y = (float*)d_out;

    unsigned short* Wc3  = (unsigned short*)d_ws;                        // 131072 B
    unsigned short* Wg3  = (unsigned short*)((char*)d_ws + 131072);      // 262144 B
    float*          bsum = (float*)((char*)d_ws + 393216);               // 1024 B
    unsigned short* xb   = (unsigned short*)((char*)d_ws + 394240);      // 60,817,408 B

    hipLaunchKernelGGL(hetconv_prep_all, dim3(1936), dim3(512), 0, stream,
                       x, W, b, xb, Wc3, Wg3, bsum);
    hipLaunchKernelGGL(hetconv_main, dim3(256), dim3(1024), 0, stream,
                       xb, Wc3, Wg3, bsum, y);
}

// Round 16
// 113.665 us; speedup vs baseline: 2.0688x; 2.0648x over previous
//
#include <hip/hip_runtime.h>
#include <hip/hip_bf16.h>

#define BATCH 32
#define CIN   256
#define COUT  256
#define Hd    56
#define Wd    56
#define HW    (Hd*Wd)

typedef __attribute__((ext_vector_type(8))) short bf16x8;
typedef __attribute__((ext_vector_type(4))) float f32x4;

typedef const __attribute__((address_space(1))) void* gas1_t;
typedef __attribute__((address_space(3))) void* las3_t;

__device__ __forceinline__ unsigned short f2bf_rne(float f) {
    unsigned u = __builtin_bit_cast(unsigned, f);
    u += 0x7fffu + ((u >> 16) & 1u);
    return (unsigned short)(u >> 16);
}

// ---------------------------------------------------------------------------
// Fused prep (R12-proven): blocks [0,1856) xconv | [1856,1904) wprep |
// [1904,1936) bsum.
// ---------------------------------------------------------------------------
__global__ __launch_bounds__(512) void hetconv_prep_all(const float* __restrict__ x,
                                                        const float* __restrict__ W,
                                                        const float* __restrict__ bb_,
                                                        unsigned short* __restrict__ xb,
                                                        unsigned short* __restrict__ Wc3,
                                                        unsigned short* __restrict__ Wg3,
                                                        float* __restrict__ bsum) {
    const int bid = blockIdx.x;
    const int tid = threadIdx.x;
    const int lane = tid & 63;
    const int wid  = tid >> 6;

    if (bid < 1856) {                    // ---- xconv ----
        const int b  = bid / 58;
        const int pr = bid % 58;
        const int octG = tid >> 4;       // [0,32)
        const int q    = tid & 15;       // col quad; 14,15 write zeros
        const int pass = octG >> 4;
        const int g    = octG & 15;
        const int grow = pr - 1;
        const bool ok = (grow >= 0) && (grow < Hd) && (q < 14);
        const size_t base = ((size_t)(b * 2 + pass) * 58 + pr) * 8192;
        const float* xrow = x + (size_t)b * CIN * HW + (size_t)grow * Wd + q * 4;

        f32x4 v[8];
        #pragma unroll
        for (int e = 0; e < 8; ++e) {
            int kp = pass * 128 + g * 8 + e;
            int ic = ((kp & 63) << 2) | (kp >> 6);
            v[e] = ok ? *reinterpret_cast<const f32x4*>(xrow + (size_t)ic * HW)
                      : f32x4{0.f, 0.f, 0.f, 0.f};
        }
        #pragma unroll
        for (int i = 0; i < 4; ++i) {
            int col = q * 4 + i;
            bf16x8 pk;
            #pragma unroll
            for (int e = 0; e < 8; ++e) pk[e] = (short)f2bf_rne(v[e][i]);
            __builtin_nontemporal_store(pk,
                reinterpret_cast<bf16x8*>(xb + base + col * 128 + ((g ^ (col & 7)) * 8)));
        }
    } else if (bid < 1904) {             // ---- wprep: 8 chunks per block ----
        const int u = (bid - 1856) * 8 + wid;    // [0,384)
        const int l15 = lane & 15;
        const int l4  = lane >> 4;
        if (u < 128) {                   // Wc3: chunk = ((r*2+p)*4+ks)*4+mf
            const int mf = u & 3;
            const int ks = (u >> 2) & 3;
            const int p  = (u >> 4) & 1;
            const int r  = u >> 5;
            const int np = r * 64 + mf * 16 + l15;
            const int n  = ((np & 63) << 2) | r;
            #pragma unroll
            for (int e = 0; e < 8; ++e) {
                int kp = p * 128 + ks * 32 + l4 * 8 + e;
                int ic = ((kp & 63) << 2) | (kp >> 6);
                Wc3[u * 512 + lane * 8 + e] = f2bf_rne(W[(n * CIN + ic) * 9 + 4]);
            }
        } else {                         // Wg3: chunk = ((r*8+t8)*2+ks2)*4+mf
            const int u2 = u - 128;
            const int mf  = u2 & 3;
            const int ks2 = (u2 >> 2) & 1;
            const int t8  = (u2 >> 3) & 7;
            const int r   = u2 >> 6;
            const int np = r * 64 + mf * 16 + l15;
            const int n  = ((np & 63) << 2) | r;
            const int tap = t8 + (t8 >= 4);
            #pragma unroll
            for (int e = 0; e < 8; ++e) {
                int j  = ks2 * 32 + l4 * 8 + e;
                int ic = (j << 2) | r;
                Wg3[u2 * 512 + lane * 8 + e] = f2bf_rne(W[(n * CIN + ic) * 9 + tap]);
            }
        }
    } else {                             // ---- bsum: 8 np per block ----
        const int np = (bid - 1904) * 8 + wid;   // [0,256)
        const int n = ((np & 63) << 2) | (np >> 6);
        float s = 0.f;
        for (int i = lane; i < CIN; i += 64) s += bb_[n * CIN + i];
        #pragma unroll
        for (int off = 32; off > 0; off >>= 1) s += __shfl_down(s, off, 64);
        if (lane == 0) bsum[np] = s;
    }
}

// ---------------------------------------------------------------------------
// Main (R12 platform + 2-round xs-reuse epilogue + XCD swizzle):
// 896 blocks x 1024 threads = 16 waves = (h, mh, r); per-wave 32 out-ch x
// 64 cols, acc[2][4] = 32 AGPR (+~56 arch VGPR = 88 unified -> 16 waves/CU).
// Stage both 64 KB pass-slabs, ONE vmcnt(0)+barrier, unbroken dense+grouped
// MFMA stream (no mid barrier; per-wave totals balanced at 192 MFMA), then
// 2-round epilogue reusing the dead xs slabs as 59 KB scratch.
// ---------------------------------------------------------------------------
__global__ __launch_bounds__(1024, 2) void hetconv_main(const unsigned short* __restrict__ xb,
                             const unsigned short* __restrict__ Wc3,
                             const unsigned short* __restrict__ Wg3,
                             const float* __restrict__ bsum,
                             float* __restrict__ y) {
    __shared__ unsigned short xs[2][32768];   // 2 x 64 KB slabs (epilogue reuses)

    const int bid  = blockIdx.x;
    const int work = (bid & 7) * 112 + (bid >> 3);   // XCD-contiguous (896 = 8*112)
    const int b    = work / 28;
    const int R0   = (work % 28) * 2;
    const int tid = threadIdx.x;
    const int lane = tid & 63;
    const int wid  = tid >> 6;        // [0,16)
    const int h  = wid & 1;
    const int mh = (wid >> 1) & 1;
    const int r  = wid >> 2;
    const int l15 = lane & 15;
    const int l4  = lane >> 4;

    f32x4 acc[2][4];
    #pragma unroll
    for (int i = 0; i < 2; ++i)
        #pragma unroll
        for (int j = 0; j < 4; ++j) acc[i][j] = f32x4{0.f, 0.f, 0.f, 0.f};

    // ---- stage both passes (8 x 16B per thread), single drain ----
    #pragma unroll
    for (int pass = 0; pass < 2; ++pass) {
        const unsigned short* slab = xb + ((size_t)(b * 2 + pass) * 58 + R0) * 8192;
        #pragma unroll
        for (int rd = 0; rd < 4; ++rd) {
            int vbase = rd * 1024 + wid * 64;     // 16B-unit index, wave-uniform
            __builtin_amdgcn_global_load_lds(
                (gas1_t)(slab + (size_t)(vbase + lane) * 8),
                (las3_t)(xs[pass] + vbase * 8), 16, 0, 0);
        }
    }
    asm volatile("s_waitcnt vmcnt(0)" ::: "memory");
    __builtin_amdgcn_s_barrier();

    // ---- both passes, one unbroken MFMA stream (R12-proven) ----
    #pragma unroll
    for (int pass = 0; pass < 2; ++pass) {
        const unsigned short* xsb = xs[pass];

        // dense center-tap GEMM: 4 K-steps of 32 channels
        {
            const int srow = (h + 1) * 64;
            #pragma unroll
            for (int ks = 0; ks < 4; ++ks) {
                bf16x8 a[2];
                #pragma unroll
                for (int mf = 0; mf < 2; ++mf) {
                    int chunk = ((r * 2 + pass) * 4 + ks) * 4 + mh * 2 + mf;
                    a[mf] = *reinterpret_cast<const bf16x8*>(
                        Wc3 + ((size_t)chunk << 9) + lane * 8);
                }
                #pragma unroll
                for (int nf = 0; nf < 4; ++nf) {
                    int s = srow + nf * 16 + l15;
                    int o = ks * 4 + l4;
                    int addr = s * 256 + ((o ^ (s & 7)) << 4);
                    bf16x8 bbv = *reinterpret_cast<const bf16x8*>(
                        reinterpret_cast<const char*>(xsb) + addr);
                    #pragma unroll
                    for (int mf = 0; mf < 2; ++mf)
                        acc[mf][nf] = __builtin_amdgcn_mfma_f32_16x16x32_bf16(
                            a[mf], bbv, acc[mf][nf], 0, 0, 0);
                }
            }
        }

        // grouped off-center taps (waves whose residue is in this pass)
        if ((r >> 1) == pass) {
            const int cbase = (r & 1) * 64;
            #pragma unroll
            for (int t8 = 0; t8 < 8; ++t8) {
                const int tap = t8 + (t8 >= 4);
                const int dy = tap / 3 - 1;
                const int dx = tap % 3 - 1;
                const int srow = (h + 1 + dy) * 64;
                #pragma unroll
                for (int ks2 = 0; ks2 < 2; ++ks2) {
                    bf16x8 a[2];
                    #pragma unroll
                    for (int mf = 0; mf < 2; ++mf) {
                        int chunk = ((r * 8 + t8) * 2 + ks2) * 4 + mh * 2 + mf;
                        a[mf] = *reinterpret_cast<const bf16x8*>(
                            Wg3 + ((size_t)chunk << 9) + lane * 8);
                    }
                    #pragma unroll
                    for (int nf = 0; nf < 4; ++nf) {
                        int c2 = nf * 16 + l15 + dx;
                        c2 = ((unsigned)c2 < 64u) ? c2 : 56;   // col 56 is zero pad
                        int s = srow + c2;
                        int o = ((cbase + ks2 * 32) >> 3) + l4;
                        int addr = s * 256 + ((o ^ (s & 7)) << 4);
                        bf16x8 bbv = *reinterpret_cast<const bf16x8*>(
                            reinterpret_cast<const char*>(xsb) + addr);
                        #pragma unroll
                        for (int mf = 0; mf < 2; ++mf)
                            acc[mf][nf] = __builtin_amdgcn_mfma_f32_16x16x32_bf16(
                                a[mf], bbv, acc[mf][nf], 0, 0, 0);
                    }
                }
            }
        }
    }
    __syncthreads();                      // slab reads done; xs now reusable

    // ---- epilogue: 2 rounds of 128 channels via xs scratch (R10-proven) ----
    float* lf = reinterpret_cast<float*>(xs[0]);
    #pragma unroll
    for (int q = 0; q < 2; ++q) {
        if ((r >> 1) == q) {
            #pragma unroll
            for (int mf = 0; mf < 2; ++mf) {
                #pragma unroll
                for (int j = 0; j < 4; ++j) {
                    int chL = (r & 1) * 64 + mh * 32 + mf * 16 + l4 * 4 + j;
                    float bias = bsum[q * 128 + chL];
                    #pragma unroll
                    for (int nf = 0; nf < 4; ++nf) {
                        int col = nf * 16 + l15;
                        if (col < Wd)
                            lf[chL * 116 + h * 56 + col] = acc[mf][nf][j] + bias;
                    }
                }
            }
        }
        __syncthreads();
        #pragma unroll
        for (int it = 0; it < 4; ++it) {
            int v = it * 1024 + tid;           // 128 chL x 28 float4
            if (v < 3584) {
                int chL = v / 28;
                int f   = v % 28;
                int h2  = (f >= 14) ? 1 : 0;
                int colS = (f - h2 * 14) * 4;
                int n = ((chL & 63) << 2) | (q * 2 + (chL >> 6));
                f32x4 val = *reinterpret_cast<const f32x4*>(lf + chL * 116 + f * 4);
                __builtin_nontemporal_store(val, reinterpret_cast<f32x4*>(
                    y + (((size_t)b * COUT + n) * Hd + (R0 + h2)) * Wd + colS));
            }
        }
        __syncthreads();
    }
}

extern "C" void kernel_launch(void* const* d_in, const int* in_sizes, int n_in,
                              void* d_out, int out_size, void* d_ws, size_t ws_size,
                              hipStream_t stream) {
    const float* x = (const float*)d_in[0];
    const float* W = (const float*)d_in[1];
    const float* b = (const float*)d_in[2];
    float* y = (float*)d_out;

    unsigned short* Wc3  = (unsigned short*)d_ws;                        // 131072 B
    unsigned short* Wg3  = (unsigned short*)((char*)d_ws + 131072);      // 262144 B
    float*          bsum = (float*)((char*)d_ws + 393216);               // 1024 B
    unsigned short* xb   = (unsigned short*)((char*)d_ws + 394240);      // 60,817,408 B

    hipLaunchKernelGGL(hetconv_prep_all, dim3(1936), dim3(512), 0, stream,
                       x, W, b, xb, Wc3, Wg3, bsum);
    hipLaunchKernelGGL(hetconv_main, dim3(BATCH * 28), dim3(1024), 0, stream,
                       xb, Wc3, Wg3, bsum, y);
}